// Round 4
// baseline (794.717 us; speedup 1.0000x reference)
//
#include <hip/hip_runtime.h>

// out[m][n] = sum_k X[m][k] * Wq[n][k] * scale[n] + bias[n]
// M=8192, N=4096, K=4096. X fp32 [M][K]; Wq int32 ternary [N][K];
// scale fp32 [N]; bias fp32 [N]; Out fp32 [M][N].
//
// Round 4: FULLY FUSED single kernel. fp32->bf16 (X) and int32->bf16 (W)
// conversion happens in the GEMM staging path: global loads for tile k+1
// are issued before compute on tile k (register prefetch), converted and
// written to the other LDS buffer after compute, one barrier per iter.
// This removes the separate convert dispatch (~74 us) entirely.
// LDS layout identical to round 3: 128 B rows, XOR-swizzled 16 B chunks
// (chunk c of row r at slot c ^ (r&7)) -> 0 bank conflicts, b128 everywhere.

#define MDIM 8192
#define NDIM 4096
#define KDIM 4096
#define BM 128
#define BN 128
#define BK 64
#define NITER (KDIM / BK)  // 64

typedef __bf16 bf16x8 __attribute__((ext_vector_type(8)));
typedef float f32x4 __attribute__((ext_vector_type(4)));

__global__ __launch_bounds__(256, 2)
void gemm_fused(const float* __restrict__ X, const int* __restrict__ Wq,
                const float* __restrict__ scale, const float* __restrict__ bias,
                float* __restrict__ Out) {
    __shared__ unsigned short As[2][BM * BK];  // 2 x 16 KB bf16
    __shared__ unsigned short Bs[2][BN * BK];  // 2 x 16 KB bf16

    const int tid  = threadIdx.x;
    const int lane = tid & 63;
    const int wave = tid >> 6;
    const int quad = lane >> 4;
    const int l16  = lane & 15;
    const int wm   = (wave >> 1) * 64;
    const int wn   = (wave & 1) * 64;

    const int m0 = blockIdx.y * BM;
    const int n0 = blockIdx.x * BN;

    // ---- staging mapping ----
    // pair id P = tid + j*256, j=0..3. Each pair = 8 source elements (32 B
    // fp32/i32 = two 16 B loads) -> one 16 B bf16 LDS chunk.
    // row = P>>3 (8 pairs per 64-elem row), chunk c = P&7, swizzled c^(row&7).
    const float* pA[4];
    const int*   pB[4];
    int ldsoff[4];  // ushort index into As/Bs row-major [128][64]
#pragma unroll
    for (int j = 0; j < 4; j++) {
        const int P   = tid + j * 256;
        const int row = P >> 3;
        const int c   = P & 7;
        const int sc  = c ^ (row & 7);
        pA[j] = X  + (size_t)(m0 + row) * KDIM + c * 8;
        pB[j] = Wq + (size_t)(n0 + row) * KDIM + c * 8;
        ldsoff[j] = row * 64 + sc * 8;
    }

    f32x4 ra[8];
    int4  rb[8];

    auto load_regs = [&](int kt) {
#pragma unroll
        for (int j = 0; j < 4; j++) {
            ra[2 * j]     = *(const f32x4*)(pA[j] + kt);
            ra[2 * j + 1] = *(const f32x4*)(pA[j] + kt + 4);
        }
#pragma unroll
        for (int j = 0; j < 4; j++) {
            rb[2 * j]     = *(const int4*)(pB[j] + kt);
            rb[2 * j + 1] = *(const int4*)(pB[j] + kt + 4);
        }
    };

    auto store_lds = [&](int buf) {
#pragma unroll
        for (int j = 0; j < 4; j++) {
            bf16x8 va;
            va[0] = (__bf16)ra[2 * j].x;     va[1] = (__bf16)ra[2 * j].y;
            va[2] = (__bf16)ra[2 * j].z;     va[3] = (__bf16)ra[2 * j].w;
            va[4] = (__bf16)ra[2 * j + 1].x; va[5] = (__bf16)ra[2 * j + 1].y;
            va[6] = (__bf16)ra[2 * j + 1].z; va[7] = (__bf16)ra[2 * j + 1].w;
            *(bf16x8*)&As[buf][ldsoff[j]] = va;
            bf16x8 vb;
            vb[0] = (__bf16)(float)rb[2 * j].x;     vb[1] = (__bf16)(float)rb[2 * j].y;
            vb[2] = (__bf16)(float)rb[2 * j].z;     vb[3] = (__bf16)(float)rb[2 * j].w;
            vb[4] = (__bf16)(float)rb[2 * j + 1].x; vb[5] = (__bf16)(float)rb[2 * j + 1].y;
            vb[6] = (__bf16)(float)rb[2 * j + 1].z; vb[7] = (__bf16)(float)rb[2 * j + 1].w;
            *(bf16x8*)&Bs[buf][ldsoff[j]] = vb;
        }
    };

    f32x4 acc[4][4];
#pragma unroll
    for (int i = 0; i < 4; i++)
#pragma unroll
        for (int j = 0; j < 4; j++)
            acc[i][j] = (f32x4){0.f, 0.f, 0.f, 0.f};

    const int sw = l16 & 7;

    auto compute = [&](int buf) {
#pragma unroll
        for (int h = 0; h < 2; h++) {
            bf16x8 af[4], bf[4];
#pragma unroll
            for (int mt = 0; mt < 4; mt++) {
                const int row = wm + mt * 16 + l16;
                af[mt] = *(const bf16x8*)((const char*)As[buf] + row * 128 +
                                          ((h * 4 + quad) ^ sw) * 16);
            }
#pragma unroll
            for (int nt = 0; nt < 4; nt++) {
                const int row = wn + nt * 16 + l16;
                bf[nt] = *(const bf16x8*)((const char*)Bs[buf] + row * 128 +
                                          ((h * 4 + quad) ^ sw) * 16);
            }
#pragma unroll
            for (int mt = 0; mt < 4; mt++)
#pragma unroll
                for (int nt = 0; nt < 4; nt++)
                    acc[mt][nt] = __builtin_amdgcn_mfma_f32_16x16x32_bf16(
                        af[mt], bf[nt], acc[mt][nt], 0, 0, 0);
        }
    };

    // prologue: fill buffer 0
    load_regs(0);
    store_lds(0);
    __syncthreads();

    for (int it = 0; it < NITER; it++) {
        if (it + 1 < NITER) load_regs((it + 1) * BK);  // issue loads early
        compute(it & 1);                               // MFMA on current buf
        if (it + 1 < NITER) store_lds((it + 1) & 1);   // convert + fill other buf
        __syncthreads();
    }

    // epilogue: C/D layout col = lane&15, row = quad*4 + r (verified)
#pragma unroll
    for (int nt = 0; nt < 4; nt++) {
        const int n = n0 + wn + nt * 16 + l16;
        const float sc = scale[n];
        const float bi = bias[n];
#pragma unroll
        for (int mt = 0; mt < 4; mt++) {
#pragma unroll
            for (int r = 0; r < 4; r++) {
                const int m = m0 + wm + mt * 16 + quad * 4 + r;
                Out[(size_t)m * NDIM + n] = acc[mt][nt][r] * sc + bi;
            }
        }
    }
}

extern "C" void kernel_launch(void* const* d_in, const int* in_sizes, int n_in,
                              void* d_out, int out_size, void* d_ws, size_t ws_size,
                              hipStream_t stream) {
    const float* x     = (const float*)d_in[0];
    const int*   wq    = (const int*)d_in[1];
    const float* scale = (const float*)d_in[2];
    const float* bias  = (const float*)d_in[3];
    float* out = (float*)d_out;

    dim3 grid(NDIM / BN, MDIM / BM);  // (32, 64): A-panel sharers adjacent
    gemm_fused<<<grid, dim3(256), 0, stream>>>(x, wq, scale, bias, out);
}